// Round 6
// baseline (182.897 us; speedup 1.0000x reference)
//
#include <hip/hip_runtime.h>

// SWD18: per-feature cyclic window-of-5 sort (reduction verified absmax=0, R1-R5):
// for column i, sort rows {5m + (i%5) + j mod L, j=0..4} ascending, in place.
// q, k are dead inputs.
//
// R6: attack L2-miss read amplification. R5 (one-shot, 1 group/thread) re-read
// each row-group 3x, and neighbor-group blocks land on different XCDs
// (round-robin dispatch) -> halo reads miss L2, served by L3 at the same
// ~6.6 TB/s service rate the harness fill kernel tops out at:
// (3*64 + 64) MB = 256 MB / 6.6 TB/s = 39 us = exactly R5's time.
// Here: 4 output groups per thread (load 30 rows upfront, amp 1.5x) and TWO
// adjacent strips per block so strip-boundary halos hit L1/L2 on the same CU
// -> external (L2-miss) read amp 1.25x. Traffic 80+64 = 144 MB -> ~22 us.
// __launch_bounds__(256,2): 256-VGPR budget so all 30 float4 loads stay in
// flight (rows[30] = 120 VGPRs).

constexpr int L = 4000;
constexpr int D = 512;
constexpr int NCG = D / 4;            // 128 float4 column-groups
constexpr int GPT = 4;                // output groups per thread
constexpr int SROWS = 5 * GPT;        // 20 output rows per thread (strip)
constexpr int NSTRIPS = L / SROWS;    // 200 strips per batch

typedef float vf4 __attribute__((ext_vector_type(4)));

// optimal 9-comparator sorting network for 5, ascending
#define CE(a, b) { float lo_ = fminf(a, b); float hi_ = fmaxf(a, b); (a) = lo_; (b) = hi_; }

// One column (component C of the vf4 rows), runtime residue RC.
// pg/cu/ng = 5-row groups g-1, g, g+1 at this column slot.
// Window A = g-1: pg[RC..4] + cu[0..RC-1]; window B = g: cu[RC..4] + ng[0..RC-1].
// Output row 5g+t = (t < RC) ? A[t+5-RC] : B[t-RC].
#define PROC_COL(C, RC)                                                            \
  {                                                                                \
    const bool e0 = (RC) == 0, e1 = (RC) == 1, e2 = (RC) == 2, e3 = (RC) == 3;     \
    float A0 = e0 ? pg[0][C] : e1 ? pg[1][C] : e2 ? pg[2][C] : e3 ? pg[3][C] : pg[4][C]; \
    float A1 = e0 ? pg[1][C] : e1 ? pg[2][C] : e2 ? pg[3][C] : e3 ? pg[4][C] : cu[0][C]; \
    float A2 = e0 ? pg[2][C] : e1 ? pg[3][C] : e2 ? pg[4][C] : e3 ? cu[0][C] : cu[1][C]; \
    float A3 = e0 ? pg[3][C] : e1 ? pg[4][C] : e2 ? cu[0][C] : e3 ? cu[1][C] : cu[2][C]; \
    float A4 = e0 ? pg[4][C] : e1 ? cu[0][C] : e2 ? cu[1][C] : e3 ? cu[2][C] : cu[3][C]; \
    float B0 = e0 ? cu[0][C] : e1 ? cu[1][C] : e2 ? cu[2][C] : e3 ? cu[3][C] : cu[4][C]; \
    float B1 = e0 ? cu[1][C] : e1 ? cu[2][C] : e2 ? cu[3][C] : e3 ? cu[4][C] : ng[0][C]; \
    float B2 = e0 ? cu[2][C] : e1 ? cu[3][C] : e2 ? cu[4][C] : e3 ? ng[0][C] : ng[1][C]; \
    float B3 = e0 ? cu[3][C] : e1 ? cu[4][C] : e2 ? ng[0][C] : e3 ? ng[1][C] : ng[2][C]; \
    float B4 = e0 ? cu[4][C] : e1 ? ng[0][C] : e2 ? ng[1][C] : e3 ? ng[2][C] : ng[3][C]; \
    CE(A0, A1) CE(A3, A4) CE(A2, A4) CE(A2, A3) CE(A1, A4)                         \
    CE(A0, A3) CE(A0, A2) CE(A1, A3) CE(A1, A2)                                    \
    CE(B0, B1) CE(B3, B4) CE(B2, B4) CE(B2, B3) CE(B1, B4)                         \
    CE(B0, B3) CE(B0, B2) CE(B1, B3) CE(B1, B2)                                    \
    fa[0][C] = e0 ? B0 : e1 ? A4 : e2 ? A3 : e3 ? A2 : A1;                         \
    fa[1][C] = e0 ? B1 : e1 ? B0 : e2 ? A4 : e3 ? A3 : A2;                         \
    fa[2][C] = e0 ? B2 : e1 ? B1 : e2 ? B0 : e3 ? A4 : A3;                         \
    fa[3][C] = e0 ? B3 : e1 ? B2 : e2 ? B1 : e3 ? B0 : A4;                         \
    fa[4][C] = e0 ? B4 : e1 ? B3 : e2 ? B2 : e3 ? B1 : B0;                         \
  }

__global__ __launch_bounds__(256, 2)
void swd18_strip4(const float* __restrict__ v, float* __restrict__ out) {
    const int cgi   = threadIdx.x & (NCG - 1);         // float4 column-group 0..127
    const int ls    = threadIdx.x >> 7;                // local strip 0/1
    const int strip = blockIdx.x * 2 + ls;             // 0..199
    const int b     = blockIdx.y;

    const float* __restrict__ vb = v   + (size_t)b * (L * D) + cgi * 4;
    float*       __restrict__ ob = out + (size_t)b * (L * D) + cgi * 4;

    // load 6 consecutive 5-row groups: [strip*20 - 5, strip*20 + 25), cyclic
    vf4 rows[30];
#pragma unroll
    for (int jg = 0; jg < 6; ++jg) {
        int gb = strip * SROWS - 5 + 5 * jg;           // group base, multiple of 5
        if (gb < 0)  gb += L;
        if (gb >= L) gb -= L;
#pragma unroll
        for (int i = 0; i < 5; ++i)
            rows[5 * jg + i] = *(const vf4*)(vb + (size_t)(gb + i) * D);
    }

    const int rc0 = (4 * cgi) % 5;
    const int rc1 = (rc0 + 1) % 5;
    const int rc2 = (rc0 + 2) % 5;
    const int rc3 = (rc0 + 3) % 5;

#pragma unroll
    for (int k = 0; k < GPT; ++k) {
        const vf4* pg = &rows[5 * k];
        const vf4* cu = &rows[5 * k + 5];
        const vf4* ng = &rows[5 * k + 10];
        vf4 fa[5];
        PROC_COL(0, rc0)
        PROC_COL(1, rc1)
        PROC_COL(2, rc2)
        PROC_COL(3, rc3)
        const int ro = strip * SROWS + 5 * k;          // output rows, never wrap
#pragma unroll
        for (int j = 0; j < 5; ++j)
            __builtin_nontemporal_store(fa[j], (vf4*)(ob + (size_t)(ro + j) * D));
    }
}

#undef PROC_COL
#undef CE

extern "C" void kernel_launch(void* const* d_in, const int* in_sizes, int n_in,
                              void* d_out, int out_size, void* d_ws, size_t ws_size,
                              hipStream_t stream) {
    // setup_inputs order: q, k, v — only v is used by the reference forward.
    const float* v = (const float*)d_in[2];
    float* out = (float*)d_out;

    const int B = in_sizes[2] / (L * D);               // 8 for the bench shape
    dim3 grid(NSTRIPS / 2, B);                         // 100 x 8 blocks of 256
    swd18_strip4<<<grid, dim3(256), 0, stream>>>(v, out);
}

// Round 7
// 179.048 us; speedup vs baseline: 1.0215x; 1.0215x over previous
//
#include <hip/hip_runtime.h>

// SWD18: per-feature cyclic window-of-5 sort (reduction verified absmax=0, R1-R6):
// for column i, sort rows {5m + (i%5) + j mod L, j=0..4} ascending, in place.
// q, k are dead inputs.
//
// R7: read-concurrency kernel. Evidence R1-R6: traffic is near-ideal
// (FETCH~46-58MB, WRITE=64MB) but service rate stuck at 2.4-3.3 TB/s while the
// harness fill kernel (write-only, no latency to hide) does 6.6 TB/s -> the
// wall is outstanding-read concurrency, not bytes. Design: scalar-column
// threads, 15 wave-uniform-row dword loads (g block-uniform -> SGPR base,
// 256B coalesced), ~15 data VGPRs -> full 8 waves/SIMD occupancy, 200 waves/CU
// over the kernel. 3x L1-level row re-read retires from L1/L2 (short latency,
// frees request queue). XCD-chunk swizzle (g-range c -> XCD c, halo-neighbor
// blocks adjacent in per-XCD sequence) makes halo re-reads L2 hits. Writes:
// 5 coalesced dword rows, each output element exactly once, nontemporal.

constexpr int L  = 4000;
constexpr int D  = 512;
constexpr int NG = L / 5;             // 800 groups
constexpr int GCHUNK = NG / 8;        // 100 groups per XCD chunk

// optimal 9-comparator sorting network for 5, ascending
#define CE(a, b) { float lo_ = fminf(a, b); float hi_ = fmaxf(a, b); (a) = lo_; (b) = hi_; }

__global__ __launch_bounds__(256)
void swd18_col(const float* __restrict__ v, float* __restrict__ out) {
    // Swizzled block decode: lin%8 selects XCD (round-robin heuristic) and also
    // the g-chunk, so each XCD streams its own 500-row slice; within an XCD,
    // consecutive seq values are (b, gin, half) ordered so g-neighbors (halo
    // sharers, seq delta 2) run temporally adjacent -> L2 hits.
    const int lin  = blockIdx.x;
    const int xcd  = lin & 7;
    const int seq  = lin >> 3;
    const int b    = seq / (2 * GCHUNK);
    const int rest = seq % (2 * GCHUNK);
    const int gin  = rest >> 1;
    const int half = rest & 1;
    const int g    = xcd * GCHUNK + gin;          // 0..799

    const int i = half * 256 + threadIdx.x;       // column 0..511

    const float* __restrict__ vb = v   + (size_t)b * (L * D);
    float*       __restrict__ ob = out + (size_t)b * (L * D);

    // Load 15 consecutive rows [5g-5, 5g+10) (cyclic) at column i.
    // Row indices are wave-uniform -> SGPR base + lane column offset,
    // 64 lanes x 4B = 256B fully-coalesced per instruction.
    float r[15];
#pragma unroll
    for (int j = 0; j < 15; ++j) {
        int row = 5 * g - 5 + j;
        if (row < 0)  row += L;
        if (row >= L) row -= L;
        r[j] = vb[(size_t)row * D + i];
    }

    const int rc = i % 5;
    const bool e0 = rc == 0, e1 = rc == 1, e2 = rc == 2, e3 = rc == 3;

    // Window A (group g-1 at residue rc): rows r[rc .. rc+4]
    // Window B (group g   at residue rc): rows r[rc+5 .. rc+9]
    float A0 = e0 ? r[0] : e1 ? r[1] : e2 ? r[2] : e3 ? r[3] : r[4];
    float A1 = e0 ? r[1] : e1 ? r[2] : e2 ? r[3] : e3 ? r[4] : r[5];
    float A2 = e0 ? r[2] : e1 ? r[3] : e2 ? r[4] : e3 ? r[5] : r[6];
    float A3 = e0 ? r[3] : e1 ? r[4] : e2 ? r[5] : e3 ? r[6] : r[7];
    float A4 = e0 ? r[4] : e1 ? r[5] : e2 ? r[6] : e3 ? r[7] : r[8];
    float B0 = e0 ? r[5] : e1 ? r[6] : e2 ? r[7] : e3 ? r[8] : r[9];
    float B1 = e0 ? r[6] : e1 ? r[7] : e2 ? r[8] : e3 ? r[9] : r[10];
    float B2 = e0 ? r[7] : e1 ? r[8] : e2 ? r[9] : e3 ? r[10] : r[11];
    float B3 = e0 ? r[8] : e1 ? r[9] : e2 ? r[10] : e3 ? r[11] : r[12];
    float B4 = e0 ? r[9] : e1 ? r[10] : e2 ? r[11] : e3 ? r[12] : r[13];

    CE(A0, A1) CE(A3, A4) CE(A2, A4) CE(A2, A3) CE(A1, A4)
    CE(A0, A3) CE(A0, A2) CE(A1, A3) CE(A1, A2)
    CE(B0, B1) CE(B3, B4) CE(B2, B4) CE(B2, B3) CE(B1, B4)
    CE(B0, B3) CE(B0, B2) CE(B1, B3) CE(B1, B2)

    // out[5g+t] = (t < rc) ? A[t+5-rc] : B[t-rc]   (same verified mux as R4-R6)
    float f0 = e0 ? B0 : e1 ? A4 : e2 ? A3 : e3 ? A2 : A1;
    float f1 = e0 ? B1 : e1 ? B0 : e2 ? A4 : e3 ? A3 : A2;
    float f2 = e0 ? B2 : e1 ? B1 : e2 ? B0 : e3 ? A4 : A3;
    float f3 = e0 ? B3 : e1 ? B2 : e2 ? B1 : e3 ? B0 : A4;
    float f4 = e0 ? B4 : e1 ? B3 : e2 ? B2 : e3 ? B1 : B0;

    // 5 coalesced dword-row stores, rows 5g..5g+4 never wrap.
    float* o = ob + (size_t)(5 * g) * D + i;
    __builtin_nontemporal_store(f0, o + 0 * D);
    __builtin_nontemporal_store(f1, o + 1 * D);
    __builtin_nontemporal_store(f2, o + 2 * D);
    __builtin_nontemporal_store(f3, o + 3 * D);
    __builtin_nontemporal_store(f4, o + 4 * D);
}

#undef CE

extern "C" void kernel_launch(void* const* d_in, const int* in_sizes, int n_in,
                              void* d_out, int out_size, void* d_ws, size_t ws_size,
                              hipStream_t stream) {
    // setup_inputs order: q, k, v — only v is used by the reference forward.
    const float* v = (const float*)d_in[2];
    float* out = (float*)d_out;

    const int B = in_sizes[2] / (L * D);          // 8 for the bench shape
    const int nblocks = B * NG * 2;               // 12800 blocks of 256
    swd18_col<<<dim3(nblocks), dim3(256), 0, stream>>>(v, out);
}

// Round 8
// 176.588 us; speedup vs baseline: 1.0357x; 1.0139x over previous
//
#include <hip/hip_runtime.h>

// SWD18: per-feature cyclic window-of-5 sort (reduction verified absmax=0, R1-R7):
// for column i, sort rows {5m + (i%5) + j mod L, j=0..4} ascending, in place.
// q, k are dead inputs.
//
// R8: kill read amplification with registers that actually stay resident.
// Unified model from R1-R7: kernel time = (L2-miss-serviced bytes incl.
// re-reads) / ~6.6 TB/s. R5/R7 re-read each row 3x -> 256 MB -> 39 us (both,
// exactly). R6 tried amp 1.5x via float4 rows[30] but VGPR_Count=60 proves the
// compiler sank the 120-VGPR array and re-loaded per group -> still ~3x.
// Scalar form: rows[30] = 30 VGPRs, nothing to sink. Thread = (b, strip, col):
// 30 upfront coalesced dword loads (rows [R0-5, R0+25), cyclic), 4 groups of
// verified A/B window mux + 9-comparator sorts, 20 coalesced NT dword stores.
// Traffic: 96 MB read + 64 MB write = 160 MB -> ~25 us predicted.
// 12800 waves = 50/CU; __launch_bounds__(256,6) caps VGPRs ~84 (no spill,
// no re-materialization).

constexpr int L  = 4000;
constexpr int D  = 512;
constexpr int SROWS   = 20;            // output rows per thread
constexpr int NSTRIPS = L / SROWS;     // 200

// optimal 9-comparator sorting network for 5, ascending
#define CE(a, b) { float lo_ = fminf(a, b); float hi_ = fmaxf(a, b); (a) = lo_; (b) = hi_; }

__global__ __launch_bounds__(256, 6)
void swd18_strip_scalar(const float* __restrict__ v, float* __restrict__ out) {
    const int half  = blockIdx.x & 1;
    const int strip = blockIdx.x >> 1;             // 0..199
    const int b     = blockIdx.y;
    const int i     = half * 256 + threadIdx.x;    // column 0..511

    const float* __restrict__ vb = v   + (size_t)b * (L * D);
    float*       __restrict__ ob = out + (size_t)b * (L * D);

    const int R0 = strip * SROWS;                  // multiple of 5

    // ---- 30 upfront loads: rows [R0-5, R0+25), cyclic only at the ends ----
    // Row index wave-uniform -> 64 lanes x 4B = 256B coalesced per instruction.
    float r[30];
    {
        int row = R0 - 5; if (row < 0) row += L;   // R0==0 wraps to L-5
#pragma unroll
        for (int j = 0; j < 5; ++j)
            r[j] = vb[(size_t)(row + j) * D + i];
    }
#pragma unroll
    for (int j = 5; j < 25; ++j)
        r[j] = vb[(size_t)(R0 + j - 5) * D + i];
    {
        int row = R0 + 20; if (row >= L) row -= L; // strip 199 wraps to 0
#pragma unroll
        for (int j = 25; j < 30; ++j)
            r[j] = vb[(size_t)(row + j - 25) * D + i];
    }

    const int rc = i % 5;
    const bool e0 = rc == 0, e1 = rc == 1, e2 = rc == 2, e3 = rc == 3;

    // ---- 4 groups; per group the verified R7 A/B window + output mux ----
#pragma unroll
    for (int k = 0; k < 4; ++k) {
        const float* p = &r[5 * k];                // pg = p[0..4], cu = p[5..9], ng = p[10..14]

        float A0 = e0 ? p[0] : e1 ? p[1] : e2 ? p[2] : e3 ? p[3] : p[4];
        float A1 = e0 ? p[1] : e1 ? p[2] : e2 ? p[3] : e3 ? p[4] : p[5];
        float A2 = e0 ? p[2] : e1 ? p[3] : e2 ? p[4] : e3 ? p[5] : p[6];
        float A3 = e0 ? p[3] : e1 ? p[4] : e2 ? p[5] : e3 ? p[6] : p[7];
        float A4 = e0 ? p[4] : e1 ? p[5] : e2 ? p[6] : e3 ? p[7] : p[8];
        float B0 = e0 ? p[5] : e1 ? p[6] : e2 ? p[7] : e3 ? p[8] : p[9];
        float B1 = e0 ? p[6] : e1 ? p[7] : e2 ? p[8] : e3 ? p[9] : p[10];
        float B2 = e0 ? p[7] : e1 ? p[8] : e2 ? p[9] : e3 ? p[10] : p[11];
        float B3 = e0 ? p[8] : e1 ? p[9] : e2 ? p[10] : e3 ? p[11] : p[12];
        float B4 = e0 ? p[9] : e1 ? p[10] : e2 ? p[11] : e3 ? p[12] : p[13];

        CE(A0, A1) CE(A3, A4) CE(A2, A4) CE(A2, A3) CE(A1, A4)
        CE(A0, A3) CE(A0, A2) CE(A1, A3) CE(A1, A2)
        CE(B0, B1) CE(B3, B4) CE(B2, B4) CE(B2, B3) CE(B1, B4)
        CE(B0, B3) CE(B0, B2) CE(B1, B3) CE(B1, B2)

        // out[R0+5k+t] = (t < rc) ? A[t+5-rc] : B[t-rc]
        float f0 = e0 ? B0 : e1 ? A4 : e2 ? A3 : e3 ? A2 : A1;
        float f1 = e0 ? B1 : e1 ? B0 : e2 ? A4 : e3 ? A3 : A2;
        float f2 = e0 ? B2 : e1 ? B1 : e2 ? B0 : e3 ? A4 : A3;
        float f3 = e0 ? B3 : e1 ? B2 : e2 ? B1 : e3 ? B0 : A4;
        float f4 = e0 ? B4 : e1 ? B3 : e2 ? B2 : e3 ? B1 : B0;

        float* o = ob + (size_t)(R0 + 5 * k) * D + i;   // rows never wrap
        __builtin_nontemporal_store(f0, o + 0 * D);
        __builtin_nontemporal_store(f1, o + 1 * D);
        __builtin_nontemporal_store(f2, o + 2 * D);
        __builtin_nontemporal_store(f3, o + 3 * D);
        __builtin_nontemporal_store(f4, o + 4 * D);
    }
}

#undef CE

extern "C" void kernel_launch(void* const* d_in, const int* in_sizes, int n_in,
                              void* d_out, int out_size, void* d_ws, size_t ws_size,
                              hipStream_t stream) {
    // setup_inputs order: q, k, v — only v is used by the reference forward.
    const float* v = (const float*)d_in[2];
    float* out = (float*)d_out;

    const int B = in_sizes[2] / (L * D);           // 8 for the bench shape
    dim3 grid(NSTRIPS * 2, B);                     // 400 x 8 = 3200 blocks of 256
    swd18_strip_scalar<<<grid, dim3(256), 0, stream>>>(v, out);
}